// Round 1
// baseline (996.396 us; speedup 1.0000x reference)
//
#include <hip/hip_runtime.h>
#include <math.h>

#define N_ROWS 8192
#define D_DIM  256
#define C_CLS  100
#define TM 64
#define TN 64
#define KB 32
#define SJ 4          // column-range splits: grid = 128*SJ blocks, 2 blocks/CU
#define LDA 68        // padded LDS row stride (floats): 4-way staging conflicts, 16B-aligned frags

// ---------------- Kernel 0: zero the global class-pair accumulator ----------
__global__ void zero_s(float* __restrict__ Sg) {
    int i = blockIdx.x * 256 + threadIdx.x;
    if (i < C_CLS * C_CLS) Sg[i] = 0.f;
}

// ---------------- Kernel 1: row L2 normalize --------------------------------
__global__ void normalize_k(const float* __restrict__ in, float* __restrict__ out) {
    const int row = blockIdx.x;
    const int t   = threadIdx.x;            // 256 threads = D_DIM
    float v = in[row * D_DIM + t];
    float s = v * v;
#pragma unroll
    for (int off = 32; off > 0; off >>= 1) s += __shfl_down(s, off, 64);
    __shared__ float partial[4];
    if ((t & 63) == 0) partial[t >> 6] = s;
    __syncthreads();
    float tot = partial[0] + partial[1] + partial[2] + partial[3];
    float nrm = fmaxf(sqrtf(tot), 1e-12f);
    out[row * D_DIM + t] = v / nrm;
}

// ---------------- Kernel 2: fused Gram-tile -> dist -> class binning --------
__global__ __launch_bounds__(256, 2)
void main_k(const float* __restrict__ fn, const int* __restrict__ labels,
            float* __restrict__ Sg) {
    __shared__ __align__(16) float As[KB][LDA];
    __shared__ __align__(16) float Bs[KB][LDA];
    __shared__ float Sp[C_CLS * C_CLS];
    __shared__ int li[TM];
    __shared__ int lj[TN];

    const int t  = threadIdx.x;     // 0..255
    const int tx = t & 15;          // micro-tile col group
    const int ty = t >> 4;          // micro-tile row group
    const int strip = blockIdx.x & 127;
    const int js    = blockIdx.x >> 7;
    const int i0    = strip * TM;
    const int jcols = N_ROWS / SJ;  // 2048
    const int jbase = js * jcols;

    for (int c = t; c < C_CLS * C_CLS; c += 256) Sp[c] = 0.f;
    if (t < TM) li[t] = labels[i0 + t];

    // staging assignment: thread loads float4 at (row r / r+32, k-chunk kk)
    const int r  = t >> 3;          // 0..31
    const int kk = (t & 7) * 4;     // 0,4,...,28

    for (int jt = 0; jt < jcols / TN; ++jt) {
        const int j0 = jbase + jt * TN;
        __syncthreads();                       // lj reuse + Sp init (first iter)
        if (t < TN) lj[t] = labels[j0 + t];

        float acc[4][4] = {};
        for (int k0 = 0; k0 < D_DIM; k0 += KB) {
            __syncthreads();                   // As/Bs reuse
            float4 av0 = *(const float4*)&fn[(size_t)(i0 + r     ) * D_DIM + k0 + kk];
            float4 av1 = *(const float4*)&fn[(size_t)(i0 + r + 32) * D_DIM + k0 + kk];
            float4 bv0 = *(const float4*)&fn[(size_t)(j0 + r     ) * D_DIM + k0 + kk];
            float4 bv1 = *(const float4*)&fn[(size_t)(j0 + r + 32) * D_DIM + k0 + kk];
            As[kk + 0][r] = av0.x; As[kk + 1][r] = av0.y;
            As[kk + 2][r] = av0.z; As[kk + 3][r] = av0.w;
            As[kk + 0][r + 32] = av1.x; As[kk + 1][r + 32] = av1.y;
            As[kk + 2][r + 32] = av1.z; As[kk + 3][r + 32] = av1.w;
            Bs[kk + 0][r] = bv0.x; Bs[kk + 1][r] = bv0.y;
            Bs[kk + 2][r] = bv0.z; Bs[kk + 3][r] = bv0.w;
            Bs[kk + 0][r + 32] = bv1.x; Bs[kk + 1][r + 32] = bv1.y;
            Bs[kk + 2][r + 32] = bv1.z; Bs[kk + 3][r + 32] = bv1.w;
            __syncthreads();
#pragma unroll
            for (int k = 0; k < KB; ++k) {
                float4 af = *(const float4*)&As[k][ty * 4];
                float4 bf = *(const float4*)&Bs[k][tx * 4];
                float a_[4] = {af.x, af.y, af.z, af.w};
                float b_[4] = {bf.x, bf.y, bf.z, bf.w};
#pragma unroll
                for (int rr = 0; rr < 4; ++rr)
#pragma unroll
                    for (int cc = 0; cc < 4; ++cc)
                        acc[rr][cc] = fmaf(a_[rr], b_[cc], acc[rr][cc]);
            }
        }
        // epilogue: dist + binning into LDS S_part
#pragma unroll
        for (int rr = 0; rr < 4; ++rr) {
            const int la = li[ty * 4 + rr];
#pragma unroll
            for (int cc = 0; cc < 4; ++cc) {
                float g  = acc[rr][cc];
                float d2 = fmaxf(2.0f - 2.0f * g, 0.f);
                float d  = (d2 > 0.f) ? sqrtf(d2) : 0.f;
                atomicAdd(&Sp[la * C_CLS + lj[tx * 4 + cc]], d);
            }
        }
    }
    __syncthreads();
    for (int c = t; c < C_CLS * C_CLS; c += 256) {
        float v = Sp[c];
        if (v != 0.f) atomicAdd(&Sg[c], v);
    }
}

// ---------------- Kernel 3: finalize (single block) -------------------------
__global__ void finalize_k(const float* __restrict__ Sg, const int* __restrict__ labels,
                           float* __restrict__ out) {
    __shared__ int   cnt[C_CLS];
    __shared__ float rf[256];
    __shared__ int   ri[256];
    const int t = threadIdx.x;      // 256 threads
    if (t < C_CLS) cnt[t] = 0;
    __syncthreads();
    for (int i = t; i < N_ROWS; i += 256) atomicAdd(&cnt[labels[i]], 1);
    __syncthreads();

    float s_intra = 0.f; int n_intra = 0;
    if (t < C_CLS) {
        int c = cnt[t];
        if (c > 1) {
            s_intra = Sg[t * C_CLS + t] / ((float)c * (float)(c - 1));
            n_intra = 1;
        }
    }
    float s_inter = 0.f; int n_pairs = 0;
    for (int idx = t; idx < C_CLS * C_CLS; idx += 256) {
        int a = idx / C_CLS, b = idx - a * C_CLS;
        if (a < b && cnt[a] > 0 && cnt[b] > 0) {
            s_inter += Sg[idx] / ((float)cnt[a] * (float)cnt[b]);
            n_pairs += 1;
        }
    }

    // block reduction: intra
    rf[t] = s_intra; ri[t] = n_intra; __syncthreads();
    for (int s = 128; s > 0; s >>= 1) {
        if (t < s) { rf[t] += rf[t + s]; ri[t] += ri[t + s]; }
        __syncthreads();
    }
    float intra_sum = rf[0]; int intra_n = ri[0];
    __syncthreads();
    // block reduction: inter
    rf[t] = s_inter; ri[t] = n_pairs; __syncthreads();
    for (int s = 128; s > 0; s >>= 1) {
        if (t < s) { rf[t] += rf[t + s]; ri[t] += ri[t + s]; }
        __syncthreads();
    }
    if (t == 0) {
        float inter_sum = rf[0]; int pairs_n = ri[0];
        float intra = (intra_n > 0) ? intra_sum / (float)intra_n : 0.f;
        float inter = (pairs_n > 0) ? inter_sum / (float)pairs_n : 1.f;
        out[0] = fmaxf(intra - inter + 1.0f, 0.f);   // MARGIN = 1.0
    }
}

// ---------------- launch ----------------------------------------------------
extern "C" void kernel_launch(void* const* d_in, const int* in_sizes, int n_in,
                              void* d_out, int out_size, void* d_ws, size_t ws_size,
                              hipStream_t stream) {
    const float* feats  = (const float*)d_in[0];
    const int*   labels = (const int*)d_in[1];
    float* out = (float*)d_out;

    float* fn = (float*)d_ws;                                      // 8 MB normalized rows
    float* Sg = (float*)((char*)d_ws + (size_t)N_ROWS * D_DIM * sizeof(float)); // 40 KB

    zero_s<<<(C_CLS * C_CLS + 255) / 256, 256, 0, stream>>>(Sg);
    normalize_k<<<N_ROWS, D_DIM, 0, stream>>>(feats, fn);
    main_k<<<128 * SJ, 256, 0, stream>>>(fn, labels, Sg);
    finalize_k<<<1, 256, 0, stream>>>(Sg, labels, out);
}

// Round 2
// 303.369 us; speedup vs baseline: 3.2844x; 3.2844x over previous
//
#include <hip/hip_runtime.h>
#include <math.h>

#define N_ROWS 8192
#define D_DIM  256
#define C_CLS  100
#define BM 128
#define BK 32
#define NSTRIP (N_ROWS / BM)              // 64
#define NBLK (NSTRIP * (NSTRIP + 1) / 2)  // 2080
#define UPK (C_CLS * (C_CLS + 1) / 2)     // 5050 packed unordered class-pair bins

typedef __attribute__((ext_vector_type(8))) __bf16 bf16x8;
typedef __attribute__((ext_vector_type(4))) float  floatx4;

__device__ __forceinline__ unsigned short f2bf(float x) {
    unsigned int u = __float_as_uint(x);
    u += 0x7fff + ((u >> 16) & 1);        // RNE
    return (unsigned short)(u >> 16);
}

__device__ __forceinline__ void gl2lds16(const void* g, void* l) {
    __builtin_amdgcn_global_load_lds(
        (const __attribute__((address_space(1))) void*)g,
        (__attribute__((address_space(3))) void*)l, 16, 0, 0);
}

// ---------------- Kernel 0: zero the packed global accumulator --------------
__global__ void zero_s(float* __restrict__ Ug) {
    int i = blockIdx.x * 256 + threadIdx.x;
    if (i < UPK) Ug[i] = 0.f;
}

// ---------------- Kernel 1: row L2 normalize -> bf16 ------------------------
__global__ void normalize_k(const float* __restrict__ in, unsigned short* __restrict__ out) {
    const int row = blockIdx.x;
    const int t   = threadIdx.x;          // 256 threads = D_DIM
    float v = in[row * D_DIM + t];
    float s = v * v;
#pragma unroll
    for (int off = 32; off > 0; off >>= 1) s += __shfl_down(s, off, 64);
    __shared__ float partial[4];
    if ((t & 63) == 0) partial[t >> 6] = s;
    __syncthreads();
    float tot = partial[0] + partial[1] + partial[2] + partial[3];
    float inv = 1.f / fmaxf(sqrtf(tot), 1e-12f);
    out[row * D_DIM + t] = f2bf(v * inv);
}

// ---------------- Kernel 2: MFMA Gram tile -> dist -> unordered binning -----
// Tile-pair (ti <= tj). Off-diag tiles: each unordered sample pair computed
// once -> add 2d. Diag tiles: both orders computed -> add d each.
// Result: U[a,a] = S[a][a]; U[a,b] = 2*S[a][b] (a<b).
__global__ __launch_bounds__(256, 3)
void main_k(const unsigned short* __restrict__ fnb, const int* __restrict__ labels,
            float* __restrict__ Ug) {
    __shared__ __align__(16) unsigned short As[BM * BK];
    __shared__ __align__(16) unsigned short Bs[BM * BK];
    __shared__ float U[UPK];
    __shared__ int li[BM], lj[BM];

    const int t = threadIdx.x;

    // decode blockIdx -> (ti, tj) with ti <= tj
    int b = blockIdx.x, ti = 0, len = NSTRIP;
    while (b >= len) { b -= len; ++ti; --len; }
    const int tj = ti + b;
    const int i0 = ti * BM, j0 = tj * BM;

    for (int c = t; c < UPK; c += 256) U[c] = 0.f;
    if (t < BM) { li[t] = labels[i0 + t]; lj[t] = labels[j0 + t]; }

    const int lane = t & 63;
    const int w    = t >> 6;
    const int m0 = (w & 1) * 64, n0 = (w >> 1) * 64;
    const int lr = lane & 15, lq = lane >> 4;
    const int swz = (lr >> 1) & 3;         // == (row>>1)&3 since row = mult16 + lr

    // frag LDS offsets (ushort units), constant across k-iters (single buffer)
    int aoff[4], boff[4];
#pragma unroll
    for (int mb = 0; mb < 4; ++mb) aoff[mb] = (m0 + mb * 16 + lr) * BK + ((lq ^ swz) * 8);
#pragma unroll
    for (int nb = 0; nb < 4; ++nb) boff[nb] = (n0 + nb * 16 + lr) * BK + ((lq ^ swz) * 8);

    // staging: slot s holds global chunk kc = (s&3) ^ ((row>>1)&3), row = s>>2
    const int s0 = t, s1 = t + 256;
    const int r0 = s0 >> 2, kc0 = (s0 & 3) ^ ((r0 >> 1) & 3);
    const int r1 = s1 >> 2, kc1 = (s1 & 3) ^ ((r1 >> 1) & 3);

    floatx4 acc[4][4];
#pragma unroll
    for (int mb = 0; mb < 4; ++mb)
#pragma unroll
        for (int nb = 0; nb < 4; ++nb) acc[mb][nb] = 0.f;

    for (int k0 = 0; k0 < D_DIM; k0 += BK) {
        __syncthreads();   // previous iter's frag reads complete before overwrite
        gl2lds16(&fnb[(size_t)(i0 + r0) * D_DIM + k0 + kc0 * 8], &As[s0 * 8]);
        gl2lds16(&fnb[(size_t)(i0 + r1) * D_DIM + k0 + kc1 * 8], &As[s1 * 8]);
        gl2lds16(&fnb[(size_t)(j0 + r0) * D_DIM + k0 + kc0 * 8], &Bs[s0 * 8]);
        gl2lds16(&fnb[(size_t)(j0 + r1) * D_DIM + k0 + kc1 * 8], &Bs[s1 * 8]);
        __syncthreads();   // compiler drains vmcnt before s_barrier

        bf16x8 a[4], bb[4];
#pragma unroll
        for (int mb = 0; mb < 4; ++mb) a[mb]  = *(const bf16x8*)&As[aoff[mb]];
#pragma unroll
        for (int nb = 0; nb < 4; ++nb) bb[nb] = *(const bf16x8*)&Bs[boff[nb]];
#pragma unroll
        for (int mb = 0; mb < 4; ++mb)
#pragma unroll
            for (int nb = 0; nb < 4; ++nb)
                acc[mb][nb] = __builtin_amdgcn_mfma_f32_16x16x32_bf16(a[mb], bb[nb], acc[mb][nb], 0, 0, 0);
    }

    // epilogue: C/D layout col=lane&15, row=(lane>>4)*4+reg
    const bool diag = (ti == tj);
    const float wscale = diag ? 1.f : 2.f;
    int lbv[4];
#pragma unroll
    for (int nb = 0; nb < 4; ++nb) lbv[nb] = lj[n0 + nb * 16 + lr];

#pragma unroll
    for (int mb = 0; mb < 4; ++mb) {
        const int rt0 = m0 + mb * 16 + lq * 4;
        const int4 la4 = *(const int4*)&li[rt0];
#pragma unroll
        for (int r = 0; r < 4; ++r) {
            const int la = (&la4.x)[r];
            const int rt = rt0 + r;
#pragma unroll
            for (int nb = 0; nb < 4; ++nb) {
                const int ct = n0 + nb * 16 + lr;
                if (diag && rt == ct) continue;          // self-pair: dist == 0 exactly
                const float g = acc[mb][nb][r];
                const float d = sqrtf(fmaxf(2.f - 2.f * g, 0.f));
                const int lb = lbv[nb];
                const int mn = min(la, lb), mx = max(la, lb);
                const int idx = mx + ((mn * (2 * C_CLS - 1 - mn)) >> 1);
                atomicAdd(&U[idx], wscale * d);
            }
        }
    }

    __syncthreads();
    for (int c = t; c < UPK; c += 256) {
        float v = U[c];
        if (v != 0.f) atomicAdd(&Ug[c], v);
    }
}

// ---------------- Kernel 3: finalize (single block) -------------------------
__global__ void finalize_k(const float* __restrict__ U, const int* __restrict__ labels,
                           float* __restrict__ out) {
    __shared__ int   cnt[C_CLS];
    __shared__ float rf[256];
    __shared__ int   ri[256];
    const int t = threadIdx.x;
    if (t < C_CLS) cnt[t] = 0;
    __syncthreads();
    for (int i = t; i < N_ROWS; i += 256) atomicAdd(&cnt[labels[i]], 1);
    __syncthreads();

    float s_intra = 0.f; int n_intra = 0;
    if (t < C_CLS) {
        int c = cnt[t];
        if (c > 1) {
            int idx = t + ((t * (2 * C_CLS - 1 - t)) >> 1);
            s_intra = U[idx] / ((float)c * (float)(c - 1));
            n_intra = 1;
        }
    }
    float s_inter = 0.f; int n_pairs = 0;
    for (int p = t; p < C_CLS * C_CLS; p += 256) {
        int a = p / C_CLS, b2 = p - a * C_CLS;
        if (b2 > a && cnt[a] > 0 && cnt[b2] > 0) {
            int idx = b2 + ((a * (2 * C_CLS - 1 - a)) >> 1);
            s_inter += 0.5f * U[idx] / ((float)cnt[a] * (float)cnt[b2]);
            ++n_pairs;
        }
    }

    rf[t] = s_intra; ri[t] = n_intra; __syncthreads();
    for (int s = 128; s > 0; s >>= 1) {
        if (t < s) { rf[t] += rf[t + s]; ri[t] += ri[t + s]; }
        __syncthreads();
    }
    float intra_sum = rf[0]; int intra_n = ri[0];
    __syncthreads();
    rf[t] = s_inter; ri[t] = n_pairs; __syncthreads();
    for (int s = 128; s > 0; s >>= 1) {
        if (t < s) { rf[t] += rf[t + s]; ri[t] += ri[t + s]; }
        __syncthreads();
    }
    if (t == 0) {
        float inter_sum = rf[0]; int pairs_n = ri[0];
        float intra = (intra_n > 0) ? intra_sum / (float)intra_n : 0.f;
        float inter = (pairs_n > 0) ? inter_sum / (float)pairs_n : 1.f;
        out[0] = fmaxf(intra - inter + 1.0f, 0.f);   // MARGIN = 1.0
    }
}

// ---------------- launch ----------------------------------------------------
extern "C" void kernel_launch(void* const* d_in, const int* in_sizes, int n_in,
                              void* d_out, int out_size, void* d_ws, size_t ws_size,
                              hipStream_t stream) {
    const float* feats  = (const float*)d_in[0];
    const int*   labels = (const int*)d_in[1];
    float* out = (float*)d_out;

    unsigned short* fnb = (unsigned short*)d_ws;                                   // 4 MB bf16 rows
    float* Ug = (float*)((char*)d_ws + (size_t)N_ROWS * D_DIM * sizeof(unsigned short));

    zero_s<<<(UPK + 255) / 256, 256, 0, stream>>>(Ug);
    normalize_k<<<N_ROWS, D_DIM, 0, stream>>>(feats, fnb);
    main_k<<<NBLK, 256, 0, stream>>>(fnb, labels, Ug);
    finalize_k<<<1, 256, 0, stream>>>(Ug, labels, out);
}

// Round 3
// 303.212 us; speedup vs baseline: 3.2861x; 1.0005x over previous
//
#include <hip/hip_runtime.h>
#include <math.h>

#define N_ROWS 8192
#define D_DIM  256
#define C_CLS  100
#define BM 128
#define BK 32
#define NSTRIP (N_ROWS / BM)              // 64
#define NBLK (NSTRIP * (NSTRIP + 1) / 2)  // 2080
#define UPK (C_CLS * (C_CLS + 1) / 2)     // 5050 packed unordered class-pair bins
#define NCOPY 64                          // partial-U copies to de-contend global atomics

typedef __attribute__((ext_vector_type(8))) __bf16 bf16x8;
typedef __attribute__((ext_vector_type(4))) float  floatx4;

__device__ __forceinline__ unsigned short f2bf(float x) {
    unsigned int u = __float_as_uint(x);
    u += 0x7fff + ((u >> 16) & 1);        // RNE
    return (unsigned short)(u >> 16);
}

__device__ __forceinline__ void gl2lds16(const void* g, void* l) {
    __builtin_amdgcn_global_load_lds(
        (const __attribute__((address_space(1))) void*)g,
        (__attribute__((address_space(3))) void*)l, 16, 0, 0);
}

// ---------------- Kernel 1: row L2 normalize -> bf16 ------------------------
__global__ void normalize_k(const float* __restrict__ in, unsigned short* __restrict__ out) {
    const int row = blockIdx.x;
    const int t   = threadIdx.x;          // 256 threads = D_DIM
    float v = in[row * D_DIM + t];
    float s = v * v;
#pragma unroll
    for (int off = 32; off > 0; off >>= 1) s += __shfl_down(s, off, 64);
    __shared__ float partial[4];
    if ((t & 63) == 0) partial[t >> 6] = s;
    __syncthreads();
    float tot = partial[0] + partial[1] + partial[2] + partial[3];
    float inv = 1.f / fmaxf(sqrtf(tot), 1e-12f);
    out[row * D_DIM + t] = f2bf(v * inv);
}

// ---------------- Kernel 2: MFMA Gram tile -> dist -> unordered binning -----
// Tile-pair (ti <= tj). Off-diag tiles: each unordered sample pair computed
// once -> add 2d. Diag tiles: both orders computed -> add d each.
// Result: U[a,a] = S[a][a]; U[a,b] = 2*S[a][b] (a<b).
// Flush goes to one of NCOPY partial copies to kill same-address contention.
__global__ __launch_bounds__(256, 4)
void main_k(const unsigned short* __restrict__ fnb, const int* __restrict__ labels,
            float* __restrict__ Upart) {
    __shared__ __align__(16) unsigned short As[BM * BK];
    __shared__ __align__(16) unsigned short Bs[BM * BK];
    __shared__ float U[UPK];
    __shared__ int li[BM], lj[BM];

    const int t = threadIdx.x;

    // decode blockIdx -> (ti, tj) with ti <= tj
    int b = blockIdx.x, ti = 0, len = NSTRIP;
    while (b >= len) { b -= len; ++ti; --len; }
    const int tj = ti + b;
    const int i0 = ti * BM, j0 = tj * BM;

    for (int c = t; c < UPK; c += 256) U[c] = 0.f;
    if (t < BM) { li[t] = labels[i0 + t]; lj[t] = labels[j0 + t]; }

    const int lane = t & 63;
    const int w    = t >> 6;
    const int m0 = (w & 1) * 64, n0 = (w >> 1) * 64;
    const int lr = lane & 15, lq = lane >> 4;
    const int swz = (lr >> 1) & 3;         // == (row>>1)&3 since row = mult16 + lr

    // frag LDS offsets (ushort units), constant across k-iters (single buffer)
    int aoff[4], boff[4];
#pragma unroll
    for (int mb = 0; mb < 4; ++mb) aoff[mb] = (m0 + mb * 16 + lr) * BK + ((lq ^ swz) * 8);
#pragma unroll
    for (int nb = 0; nb < 4; ++nb) boff[nb] = (n0 + nb * 16 + lr) * BK + ((lq ^ swz) * 8);

    // staging: slot s holds global chunk kc = (s&3) ^ ((row>>1)&3), row = s>>2
    const int s0 = t, s1 = t + 256;
    const int r0 = s0 >> 2, kc0 = (s0 & 3) ^ ((r0 >> 1) & 3);
    const int r1 = s1 >> 2, kc1 = (s1 & 3) ^ ((r1 >> 1) & 3);

    floatx4 acc[4][4];
#pragma unroll
    for (int mb = 0; mb < 4; ++mb)
#pragma unroll
        for (int nb = 0; nb < 4; ++nb) acc[mb][nb] = 0.f;

    for (int k0 = 0; k0 < D_DIM; k0 += BK) {
        __syncthreads();   // previous iter's frag reads complete before overwrite
        gl2lds16(&fnb[(size_t)(i0 + r0) * D_DIM + k0 + kc0 * 8], &As[s0 * 8]);
        gl2lds16(&fnb[(size_t)(i0 + r1) * D_DIM + k0 + kc1 * 8], &As[s1 * 8]);
        gl2lds16(&fnb[(size_t)(j0 + r0) * D_DIM + k0 + kc0 * 8], &Bs[s0 * 8]);
        gl2lds16(&fnb[(size_t)(j0 + r1) * D_DIM + k0 + kc1 * 8], &Bs[s1 * 8]);
        __syncthreads();   // compiler drains vmcnt before s_barrier

        bf16x8 a[4], bb[4];
#pragma unroll
        for (int mb = 0; mb < 4; ++mb) a[mb]  = *(const bf16x8*)&As[aoff[mb]];
#pragma unroll
        for (int nb = 0; nb < 4; ++nb) bb[nb] = *(const bf16x8*)&Bs[boff[nb]];
#pragma unroll
        for (int mb = 0; mb < 4; ++mb)
#pragma unroll
            for (int nb = 0; nb < 4; ++nb)
                acc[mb][nb] = __builtin_amdgcn_mfma_f32_16x16x32_bf16(a[mb], bb[nb], acc[mb][nb], 0, 0, 0);
    }

    // epilogue: C/D layout col=lane&15, row=(lane>>4)*4+reg
    const bool diag = (ti == tj);
    const float wscale = diag ? 1.f : 2.f;
    int lbv[4];
#pragma unroll
    for (int nb = 0; nb < 4; ++nb) lbv[nb] = lj[n0 + nb * 16 + lr];

#pragma unroll
    for (int mb = 0; mb < 4; ++mb) {
        const int rt0 = m0 + mb * 16 + lq * 4;
        const int4 la4 = *(const int4*)&li[rt0];
#pragma unroll
        for (int r = 0; r < 4; ++r) {
            const int la = (&la4.x)[r];
            const int rt = rt0 + r;
#pragma unroll
            for (int nb = 0; nb < 4; ++nb) {
                const int ct = n0 + nb * 16 + lr;
                if (diag && rt == ct) continue;          // self-pair: dist == 0 exactly
                const float g = acc[mb][nb][r];
                const float d = sqrtf(fmaxf(2.f - 2.f * g, 0.f));
                const int lb = lbv[nb];
                const int mn = min(la, lb), mx = max(la, lb);
                const int idx = mx + ((mn * (2 * C_CLS - 1 - mn)) >> 1);
                atomicAdd(&U[idx], wscale * d);
            }
        }
    }

    __syncthreads();
    float* Udst = Upart + (size_t)(blockIdx.x & (NCOPY - 1)) * UPK;
    for (int c = t; c < UPK; c += 256) {
        float v = U[c];
        if (v != 0.f) atomicAdd(&Udst[c], v);
    }
}

// ---------------- Kernel 2.5: sum the NCOPY partials ------------------------
__global__ void reduce_k(const float* __restrict__ Upart, float* __restrict__ Ufinal) {
    const int e = blockIdx.x * 256 + threadIdx.x;
    if (e >= UPK) return;
    float s = 0.f;
#pragma unroll 8
    for (int k = 0; k < NCOPY; ++k) s += Upart[(size_t)k * UPK + e];
    Ufinal[e] = s;
}

// ---------------- Kernel 3: finalize (single block) -------------------------
__global__ void finalize_k(const float* __restrict__ U, const int* __restrict__ labels,
                           float* __restrict__ out) {
    __shared__ int   cnt[C_CLS];
    __shared__ float rf[256];
    __shared__ int   ri[256];
    const int t = threadIdx.x;
    if (t < C_CLS) cnt[t] = 0;
    __syncthreads();
    for (int i = t; i < N_ROWS; i += 256) atomicAdd(&cnt[labels[i]], 1);
    __syncthreads();

    float s_intra = 0.f; int n_intra = 0;
    if (t < C_CLS) {
        int c = cnt[t];
        if (c > 1) {
            int idx = t + ((t * (2 * C_CLS - 1 - t)) >> 1);
            s_intra = U[idx] / ((float)c * (float)(c - 1));
            n_intra = 1;
        }
    }
    float s_inter = 0.f; int n_pairs = 0;
    for (int p = t; p < C_CLS * C_CLS; p += 256) {
        int a = p / C_CLS, b2 = p - a * C_CLS;
        if (b2 > a && cnt[a] > 0 && cnt[b2] > 0) {
            int idx = b2 + ((a * (2 * C_CLS - 1 - a)) >> 1);
            s_inter += 0.5f * U[idx] / ((float)cnt[a] * (float)cnt[b2]);
            ++n_pairs;
        }
    }

    rf[t] = s_intra; ri[t] = n_intra; __syncthreads();
    for (int s = 128; s > 0; s >>= 1) {
        if (t < s) { rf[t] += rf[t + s]; ri[t] += ri[t + s]; }
        __syncthreads();
    }
    float intra_sum = rf[0]; int intra_n = ri[0];
    __syncthreads();
    rf[t] = s_inter; ri[t] = n_pairs; __syncthreads();
    for (int s = 128; s > 0; s >>= 1) {
        if (t < s) { rf[t] += rf[t + s]; ri[t] += ri[t + s]; }
        __syncthreads();
    }
    if (t == 0) {
        float inter_sum = rf[0]; int pairs_n = ri[0];
        float intra = (intra_n > 0) ? intra_sum / (float)intra_n : 0.f;
        float inter = (pairs_n > 0) ? inter_sum / (float)pairs_n : 1.f;
        out[0] = fmaxf(intra - inter + 1.0f, 0.f);   // MARGIN = 1.0
    }
}

// ---------------- launch ----------------------------------------------------
extern "C" void kernel_launch(void* const* d_in, const int* in_sizes, int n_in,
                              void* d_out, int out_size, void* d_ws, size_t ws_size,
                              hipStream_t stream) {
    const float* feats  = (const float*)d_in[0];
    const int*   labels = (const int*)d_in[1];
    float* out = (float*)d_out;

    unsigned short* fnb = (unsigned short*)d_ws;                       // 4 MB bf16 rows
    char* p = (char*)d_ws + (size_t)N_ROWS * D_DIM * sizeof(unsigned short);
    float* Upart  = (float*)p;                                         // 64*5050*4 = 1.29 MB
    float* Ufinal = (float*)(p + (size_t)NCOPY * UPK * sizeof(float)); // 20 KB

    hipMemsetAsync(Upart, 0, (size_t)NCOPY * UPK * sizeof(float), stream);
    normalize_k<<<N_ROWS, D_DIM, 0, stream>>>(feats, fnb);
    main_k<<<NBLK, 256, 0, stream>>>(fnb, labels, Upart);
    reduce_k<<<(UPK + 255) / 256, 256, 0, stream>>>(Upart, Ufinal);
    finalize_k<<<1, 256, 0, stream>>>(Ufinal, labels, out);
}

// Round 4
// 144.764 us; speedup vs baseline: 6.8829x; 2.0945x over previous
//
#include <hip/hip_runtime.h>
#include <math.h>

#define N_ROWS 8192
#define D_DIM  256
#define C_CLS  100
#define BM 128
#define BK 32
#define NSTRIP (N_ROWS / BM)              // 64
#define NBLK (NSTRIP * (NSTRIP + 1) / 2)  // 2080
#define UPK (C_CLS * (C_CLS + 1) / 2)     // 5050 packed unordered class-pair bins

typedef __attribute__((ext_vector_type(8))) __bf16 bf16x8;
typedef __attribute__((ext_vector_type(4))) float  floatx4;

__device__ __forceinline__ unsigned short f2bf(float x) {
    unsigned int u = __float_as_uint(x);
    u += 0x7fff + ((u >> 16) & 1);        // RNE
    return (unsigned short)(u >> 16);
}

__device__ __forceinline__ void gl2lds16(const void* g, void* l) {
    __builtin_amdgcn_global_load_lds(
        (const __attribute__((address_space(1))) void*)g,
        (__attribute__((address_space(3))) void*)l, 16, 0, 0);
}

// ---- K0: label histogram -> class offsets + scatter cursors + zero U -------
__global__ void hist_k(const int* __restrict__ labels, int* __restrict__ offs,
                       int* __restrict__ cursor, float* __restrict__ Ug) {
    __shared__ int cnt[C_CLS];
    const int t = threadIdx.x;
    if (t < C_CLS) cnt[t] = 0;
    __syncthreads();
    for (int i = t; i < N_ROWS; i += 256) atomicAdd(&cnt[labels[i]], 1);
    __syncthreads();
    if (t == 0) {
        int run = 0;
        for (int c = 0; c < C_CLS; ++c) { offs[c] = run; cursor[c] = run; run += cnt[c]; }
        offs[C_CLS] = run;
    }
    for (int e = t; e < UPK; e += 256) Ug[e] = 0.f;
}

// ---- K1: counting-sort scatter: dest slot per row + sorted labels ----------
__global__ void scatter_k(const int* __restrict__ labels, int* __restrict__ cursor,
                          int* __restrict__ dest, int* __restrict__ slab) {
    const int i = blockIdx.x * 256 + threadIdx.x;
    const int la = labels[i];
    const int pos = atomicAdd(&cursor[la], 1);
    dest[i] = pos;
    slab[pos] = la;
}

// ---- K2: L2-normalize rows -> bf16 at sorted slot. One wave per row. -------
__global__ void normalize_k(const float* __restrict__ in, const int* __restrict__ dest,
                            unsigned short* __restrict__ fnb) {
    const int row  = blockIdx.x * 4 + (threadIdx.x >> 6);
    const int lane = threadIdx.x & 63;
    float4 v = ((const float4*)in)[row * 64 + lane];     // 64 lanes x 16B = one row
    float s = v.x * v.x + v.y * v.y + v.z * v.z + v.w * v.w;
#pragma unroll
    for (int o = 32; o > 0; o >>= 1) s += __shfl_xor(s, o, 64);
    const float inv = 1.f / fmaxf(sqrtf(s), 1e-12f);
    const int d = dest[row];
    ushort4 o4;
    o4.x = f2bf(v.x * inv); o4.y = f2bf(v.y * inv);
    o4.z = f2bf(v.z * inv); o4.w = f2bf(v.w * inv);
    ((ushort4*)fnb)[d * 64 + lane] = o4;
}

// ---- K3: MFMA Gram tile -> dist -> segment-pair binning (sorted classes) ---
// Tile-pair (ti <= tj). Off-diag: each unordered sample pair once -> weight 2.
// Diag: both orders present -> weight 1. U[a,a]=S[a][a]; U[a,b]=2*S[a][b].
__global__ __launch_bounds__(256, 4)
void main_k(const unsigned short* __restrict__ fnb, const int* __restrict__ slab,
            const int* __restrict__ offs_g, float* __restrict__ Ug) {
    __shared__ __align__(16) unsigned short As[BM * BK];
    __shared__ __align__(16) unsigned short Bs[BM * BK];
    __shared__ int li[BM], lj[BM];
    __shared__ int soffs[C_CLS + 1];

    const int t = threadIdx.x;

    // decode blockIdx -> (ti, tj) with ti <= tj
    int b = blockIdx.x, ti = 0, len = NSTRIP;
    while (b >= len) { b -= len; ++ti; --len; }
    const int tj = ti + b;
    const int i0 = ti * BM, j0 = tj * BM;

    if (t < BM) { li[t] = slab[i0 + t]; lj[t] = slab[j0 + t]; }
    if (t < C_CLS + 1) soffs[t] = offs_g[t];

    const int lane = t & 63;
    const int w    = t >> 6;
    const int m0 = (w & 1) * 64, n0 = (w >> 1) * 64;
    const int lr = lane & 15, lq = lane >> 4;
    const int swz = (lr >> 1) & 3;

    // frag LDS offsets (ushort units), constant across k-iters (single buffer)
    int aoff[4], boff[4];
#pragma unroll
    for (int mb = 0; mb < 4; ++mb) aoff[mb] = (m0 + mb * 16 + lr) * BK + ((lq ^ swz) * 8);
#pragma unroll
    for (int nb = 0; nb < 4; ++nb) boff[nb] = (n0 + nb * 16 + lr) * BK + ((lq ^ swz) * 8);

    // staging: slot s holds global chunk kc = (s&3) ^ ((row>>1)&3), row = s>>2
    const int s0 = t, s1 = t + 256;
    const int r0 = s0 >> 2, kc0 = (s0 & 3) ^ ((r0 >> 1) & 3);
    const int r1 = s1 >> 2, kc1 = (s1 & 3) ^ ((r1 >> 1) & 3);

    floatx4 acc[4][4];
#pragma unroll
    for (int mb = 0; mb < 4; ++mb)
#pragma unroll
        for (int nb = 0; nb < 4; ++nb) acc[mb][nb] = 0.f;

    for (int k0 = 0; k0 < D_DIM; k0 += BK) {
        __syncthreads();
        gl2lds16(&fnb[(size_t)(i0 + r0) * D_DIM + k0 + kc0 * 8], &As[s0 * 8]);
        gl2lds16(&fnb[(size_t)(i0 + r1) * D_DIM + k0 + kc1 * 8], &As[s1 * 8]);
        gl2lds16(&fnb[(size_t)(j0 + r0) * D_DIM + k0 + kc0 * 8], &Bs[s0 * 8]);
        gl2lds16(&fnb[(size_t)(j0 + r1) * D_DIM + k0 + kc1 * 8], &Bs[s1 * 8]);
        __syncthreads();

        bf16x8 a[4], bb[4];
#pragma unroll
        for (int mb = 0; mb < 4; ++mb) a[mb]  = *(const bf16x8*)&As[aoff[mb]];
#pragma unroll
        for (int nb = 0; nb < 4; ++nb) bb[nb] = *(const bf16x8*)&Bs[boff[nb]];
#pragma unroll
        for (int mb = 0; mb < 4; ++mb)
#pragma unroll
            for (int nb = 0; nb < 4; ++nb)
                acc[mb][nb] = __builtin_amdgcn_mfma_f32_16x16x32_bf16(a[mb], bb[nb], acc[mb][nb], 0, 0, 0);
    }

    // ---- epilogue: convert Gram -> dist in place (C/D: col=lane&15, row=lq*4+reg)
    const bool diag = (ti == tj);
#pragma unroll
    for (int mb = 0; mb < 4; ++mb)
#pragma unroll
        for (int nb = 0; nb < 4; ++nb)
#pragma unroll
            for (int r = 0; r < 4; ++r) {
                const float g = acc[mb][nb][r];
                float dv = sqrtf(fmaxf(2.f - 2.f * g, 0.f));
                const int rt = m0 + mb * 16 + lq * 4 + r;
                const int ct = n0 + nb * 16 + lr;
                if (diag && rt == ct) dv = 0.f;          // exact self-pair zero
                acc[mb][nb][r] = dv;
            }

    // wave-uniform class ranges (rows sorted by class)
    const int cA0 = __builtin_amdgcn_readfirstlane(li[m0]);
    const int cA1 = __builtin_amdgcn_readfirstlane(li[m0 + 63]);
    const int cB0 = __builtin_amdgcn_readfirstlane(lj[n0]);
    const int cB1 = __builtin_amdgcn_readfirstlane(lj[n0 + 63]);
    const float wscale = diag ? 1.f : 2.f;

    for (int cb = cB0; cb <= cB1; ++cb) {
        const int rb0 = max(soffs[cb]     - j0, n0);
        const int rb1 = min(soffs[cb + 1] - j0, n0 + 64);
        if (rb0 >= rb1) continue;                        // empty/absent class
        // column-masked partial sums per (mb, r)
        float colsum[4][4];
#pragma unroll
        for (int mb = 0; mb < 4; ++mb)
#pragma unroll
            for (int r = 0; r < 4; ++r) colsum[mb][r] = 0.f;
#pragma unroll
        for (int nb = 0; nb < 4; ++nb) {
            const int ct = n0 + nb * 16 + lr;
            const bool ic = (ct >= rb0) & (ct < rb1);
#pragma unroll
            for (int mb = 0; mb < 4; ++mb)
#pragma unroll
                for (int r = 0; r < 4; ++r)
                    colsum[mb][r] += ic ? acc[mb][nb][r] : 0.f;
        }
        for (int ca = cA0; ca <= cA1; ++ca) {
            const int ra0 = max(soffs[ca]     - i0, m0);
            const int ra1 = min(soffs[ca + 1] - i0, m0 + 64);
            if (ra0 >= ra1) continue;
            float v = 0.f;
#pragma unroll
            for (int mb = 0; mb < 4; ++mb)
#pragma unroll
                for (int r = 0; r < 4; ++r) {
                    const int rt = m0 + mb * 16 + lq * 4 + r;
                    const bool ir = (rt >= ra0) & (rt < ra1);
                    v += ir ? colsum[mb][r] : 0.f;
                }
#pragma unroll
            for (int o = 32; o > 0; o >>= 1) v += __shfl_xor(v, o, 64);
            if (lane == 0 && v != 0.f) {
                const int mn = min(ca, cb), mx = max(ca, cb);
                const int idx = mx + ((mn * (2 * C_CLS - 1 - mn)) >> 1);
                atomicAdd(&Ug[idx], wscale * v);
            }
        }
    }
}

// ---- K4: finalize (single block; recomputes counts from original labels) ---
__global__ void finalize_k(const float* __restrict__ U, const int* __restrict__ labels,
                           float* __restrict__ out) {
    __shared__ int   cnt[C_CLS];
    __shared__ float rf[256];
    __shared__ int   ri[256];
    const int t = threadIdx.x;
    if (t < C_CLS) cnt[t] = 0;
    __syncthreads();
    for (int i = t; i < N_ROWS; i += 256) atomicAdd(&cnt[labels[i]], 1);
    __syncthreads();

    float s_intra = 0.f; int n_intra = 0;
    if (t < C_CLS) {
        int c = cnt[t];
        if (c > 1) {
            int idx = t + ((t * (2 * C_CLS - 1 - t)) >> 1);
            s_intra = U[idx] / ((float)c * (float)(c - 1));
            n_intra = 1;
        }
    }
    float s_inter = 0.f; int n_pairs = 0;
    for (int p = t; p < C_CLS * C_CLS; p += 256) {
        int a = p / C_CLS, b2 = p - a * C_CLS;
        if (b2 > a && cnt[a] > 0 && cnt[b2] > 0) {
            int idx = b2 + ((a * (2 * C_CLS - 1 - a)) >> 1);
            s_inter += 0.5f * U[idx] / ((float)cnt[a] * (float)cnt[b2]);
            ++n_pairs;
        }
    }

    rf[t] = s_intra; ri[t] = n_intra; __syncthreads();
    for (int s = 128; s > 0; s >>= 1) {
        if (t < s) { rf[t] += rf[t + s]; ri[t] += ri[t + s]; }
        __syncthreads();
    }
    float intra_sum = rf[0]; int intra_n = ri[0];
    __syncthreads();
    rf[t] = s_inter; ri[t] = n_pairs; __syncthreads();
    for (int s = 128; s > 0; s >>= 1) {
        if (t < s) { rf[t] += rf[t + s]; ri[t] += ri[t + s]; }
        __syncthreads();
    }
    if (t == 0) {
        float inter_sum = rf[0]; int pairs_n = ri[0];
        float intra = (intra_n > 0) ? intra_sum / (float)intra_n : 0.f;
        float inter = (pairs_n > 0) ? inter_sum / (float)pairs_n : 1.f;
        out[0] = fmaxf(intra - inter + 1.0f, 0.f);   // MARGIN = 1.0
    }
}

// ---- launch ----------------------------------------------------------------
extern "C" void kernel_launch(void* const* d_in, const int* in_sizes, int n_in,
                              void* d_out, int out_size, void* d_ws, size_t ws_size,
                              hipStream_t stream) {
    const float* feats  = (const float*)d_in[0];
    const int*   labels = (const int*)d_in[1];
    float* out = (float*)d_out;

    char* p = (char*)d_ws;
    unsigned short* fnb = (unsigned short*)p;  p += (size_t)N_ROWS * D_DIM * sizeof(unsigned short); // 4 MB
    int*   slab   = (int*)p;                   p += (size_t)N_ROWS * sizeof(int);                    // 32 KB
    int*   dest   = (int*)p;                   p += (size_t)N_ROWS * sizeof(int);                    // 32 KB
    int*   offs   = (int*)p;                   p += 128 * sizeof(int);
    int*   cursor = (int*)p;                   p += 128 * sizeof(int);
    float* Ug     = (float*)p;                                                                        // 20 KB

    hist_k    <<<1, 256, 0, stream>>>(labels, offs, cursor, Ug);
    scatter_k <<<N_ROWS / 256, 256, 0, stream>>>(labels, cursor, dest, slab);
    normalize_k<<<N_ROWS / 4, 256, 0, stream>>>(feats, dest, fnb);
    main_k    <<<NBLK, 256, 0, stream>>>(fnb, slab, offs, Ug);
    finalize_k<<<1, 256, 0, stream>>>(Ug, labels, out);
}

// Round 5
// 120.394 us; speedup vs baseline: 8.2761x; 1.2024x over previous
//
#include <hip/hip_runtime.h>
#include <math.h>

#define N_ROWS 8192
#define D_DIM  256
#define C_CLS  100
#define BM 128
#define BK 32
#define NSTRIP (N_ROWS / BM)              // 64
#define NBLK (NSTRIP * (NSTRIP + 1) / 2)  // 2080
#define UPK (C_CLS * (C_CLS + 1) / 2)     // 5050 packed unordered class-pair bins
#define NHB (N_ROWS / 256)                // 32 hist blocks
#define MAXSEG 4                          // class segments per 64-row window (data: <=2-3)

typedef __attribute__((ext_vector_type(8))) __bf16 bf16x8;
typedef __attribute__((ext_vector_type(4))) float  floatx4;

__device__ __forceinline__ unsigned short f2bf(float x) {
    unsigned int u = __float_as_uint(x);
    u += 0x7fff + ((u >> 16) & 1);        // RNE
    return (unsigned short)(u >> 16);
}

__device__ __forceinline__ void gl2lds16(const void* g, void* l) {
    __builtin_amdgcn_global_load_lds(
        (const __attribute__((address_space(1))) void*)g,
        (__attribute__((address_space(3))) void*)l, 16, 0, 0);
}

// ---- K0: per-block label histograms (no global atomics) --------------------
__global__ void hist_k(const int* __restrict__ labels, int* __restrict__ hist_part) {
    __shared__ int h[C_CLS];
    const int t = threadIdx.x;
    if (t < C_CLS) h[t] = 0;
    __syncthreads();
    atomicAdd(&h[labels[blockIdx.x * 256 + t]], 1);
    __syncthreads();
    if (t < C_CLS) hist_part[blockIdx.x * C_CLS + t] = h[t];
}

// ---- K1: class offsets + per-block class offsets + zero U ------------------
__global__ void scan_k(const int* __restrict__ hist_part, int* __restrict__ offs,
                       int* __restrict__ blockoffs, float* __restrict__ Ug) {
    __shared__ int tot[C_CLS];
    const int t = threadIdx.x;
    if (t < C_CLS) {
        int run = 0;
        for (int b = 0; b < NHB; ++b) {
            blockoffs[b * C_CLS + t] = run;          // intra-class prefix over blocks
            run += hist_part[b * C_CLS + t];
        }
        tot[t] = run;
    }
    __syncthreads();
    if (t == 0) {
        int run = 0;
        for (int c = 0; c < C_CLS; ++c) { offs[c] = run; run += tot[c]; }
        offs[C_CLS] = run;
    }
    for (int e = t; e < UPK; e += 256) Ug[e] = 0.f;
}

// ---- K2: contention-free deterministic counting-sort scatter ---------------
__global__ void scatter_k(const int* __restrict__ labels, const int* __restrict__ offs,
                          const int* __restrict__ blockoffs, int* __restrict__ dest,
                          int* __restrict__ slab) {
    __shared__ int cur[C_CLS];
    const int t = threadIdx.x;
    if (t < C_CLS) cur[t] = offs[t] + blockoffs[blockIdx.x * C_CLS + t];
    __syncthreads();
    const int i  = blockIdx.x * 256 + t;
    const int la = labels[i];
    const int pos = atomicAdd(&cur[la], 1);          // rank within this block's class run
    dest[i] = pos;
    slab[pos] = la;
}

// ---- K3: L2-normalize rows -> bf16 at sorted slot. One wave per row. -------
__global__ void normalize_k(const float* __restrict__ in, const int* __restrict__ dest,
                            unsigned short* __restrict__ fnb) {
    const int row  = blockIdx.x * 4 + (threadIdx.x >> 6);
    const int lane = threadIdx.x & 63;
    float4 v = ((const float4*)in)[row * 64 + lane];
    float s = v.x * v.x + v.y * v.y + v.z * v.z + v.w * v.w;
#pragma unroll
    for (int o = 32; o > 0; o >>= 1) s += __shfl_xor(s, o, 64);
    const float inv = 1.f / fmaxf(sqrtf(s), 1e-12f);
    const int d = dest[row];
    ushort4 o4;
    o4.x = f2bf(v.x * inv); o4.y = f2bf(v.y * inv);
    o4.z = f2bf(v.z * inv); o4.w = f2bf(v.w * inv);
    ((ushort4*)fnb)[d * 64 + lane] = o4;
}

// ---- K4: MFMA Gram tile -> dist -> segment binning (no shuffle chains) -----
__global__ __launch_bounds__(256, 4)
void main_k(const unsigned short* __restrict__ fnb, const int* __restrict__ slab,
            const int* __restrict__ offs_g, float* __restrict__ Ug) {
    __shared__ __align__(16) unsigned short As[BM * BK];
    __shared__ __align__(16) unsigned short Bs[BM * BK];
    __shared__ float red[4][MAXSEG * MAXSEG][65];   // [wave][combo][lane], pad->2-way free
    __shared__ int soffs[C_CLS + 1];
    __shared__ int meta[4][4];                      // per wave: cA0, cB0, segsA, segsB

    const int t = threadIdx.x;

    int b = blockIdx.x, ti = 0, len = NSTRIP;
    while (b >= len) { b -= len; ++ti; --len; }
    const int tj = ti + b;
    const int i0 = ti * BM, j0 = tj * BM;

    if (t < C_CLS + 1) soffs[t] = offs_g[t];
    for (int e = t; e < 4 * MAXSEG * MAXSEG * 65; e += 256) (&red[0][0][0])[e] = 0.f;

    const int lane = t & 63;
    const int w    = t >> 6;
    const int m0 = (w & 1) * 64, n0 = (w >> 1) * 64;
    const int lr = lane & 15, lq = lane >> 4;
    const int swz = (lr >> 1) & 3;

    int aoff[4], boff[4];
#pragma unroll
    for (int mb = 0; mb < 4; ++mb) aoff[mb] = (m0 + mb * 16 + lr) * BK + ((lq ^ swz) * 8);
#pragma unroll
    for (int nb = 0; nb < 4; ++nb) boff[nb] = (n0 + nb * 16 + lr) * BK + ((lq ^ swz) * 8);

    const int s0 = t, s1 = t + 256;
    const int r0 = s0 >> 2, kc0 = (s0 & 3) ^ ((r0 >> 1) & 3);
    const int r1 = s1 >> 2, kc1 = (s1 & 3) ^ ((r1 >> 1) & 3);

    floatx4 acc[4][4];
#pragma unroll
    for (int mb = 0; mb < 4; ++mb)
#pragma unroll
        for (int nb = 0; nb < 4; ++nb) acc[mb][nb] = 0.f;

    for (int k0 = 0; k0 < D_DIM; k0 += BK) {
        __syncthreads();
        gl2lds16(&fnb[(size_t)(i0 + r0) * D_DIM + k0 + kc0 * 8], &As[s0 * 8]);
        gl2lds16(&fnb[(size_t)(i0 + r1) * D_DIM + k0 + kc1 * 8], &As[s1 * 8]);
        gl2lds16(&fnb[(size_t)(j0 + r0) * D_DIM + k0 + kc0 * 8], &Bs[s0 * 8]);
        gl2lds16(&fnb[(size_t)(j0 + r1) * D_DIM + k0 + kc1 * 8], &Bs[s1 * 8]);
        __syncthreads();

        bf16x8 a[4], bb[4];
#pragma unroll
        for (int mb = 0; mb < 4; ++mb) a[mb]  = *(const bf16x8*)&As[aoff[mb]];
#pragma unroll
        for (int nb = 0; nb < 4; ++nb) bb[nb] = *(const bf16x8*)&Bs[boff[nb]];
#pragma unroll
        for (int mb = 0; mb < 4; ++mb)
#pragma unroll
            for (int nb = 0; nb < 4; ++nb)
                acc[mb][nb] = __builtin_amdgcn_mfma_f32_16x16x32_bf16(a[mb], bb[nb], acc[mb][nb], 0, 0, 0);
    }

    // ---- Gram -> dist in place (C/D: col=lane&15, row=lq*4+reg) ----
    const bool diag = (ti == tj);
#pragma unroll
    for (int mb = 0; mb < 4; ++mb)
#pragma unroll
        for (int nb = 0; nb < 4; ++nb)
#pragma unroll
            for (int r = 0; r < 4; ++r) {
                const float g = acc[mb][nb][r];
                float dv = __builtin_amdgcn_sqrtf(fmaxf(2.f - 2.f * g, 0.f));
                const int rt = m0 + mb * 16 + lq * 4 + r;
                const int ct = n0 + nb * 16 + lr;
                if (diag && rt == ct) dv = 0.f;
                acc[mb][nb][r] = dv;
            }

    // wave-uniform class ranges from sorted labels (broadcast loads)
    const int cA0 = __builtin_amdgcn_readfirstlane(slab[i0 + m0]);
    const int cA1 = __builtin_amdgcn_readfirstlane(slab[i0 + m0 + 63]);
    const int cB0 = __builtin_amdgcn_readfirstlane(slab[j0 + n0]);
    const int cB1 = __builtin_amdgcn_readfirstlane(slab[j0 + n0 + 63]);
    const int segsA = cA1 - cA0 + 1, segsB = cB1 - cB0 + 1;
    if (lane == 0) { meta[w][0] = cA0; meta[w][1] = cB0; meta[w][2] = segsA; meta[w][3] = segsB; }
    const float wscale = diag ? 1.f : 2.f;

    // row totals -> rem; per-cb colsum via subtraction telescope
    float rem[4][4];
#pragma unroll
    for (int mb = 0; mb < 4; ++mb)
#pragma unroll
        for (int r = 0; r < 4; ++r)
            rem[mb][r] = acc[mb][0][r] + acc[mb][1][r] + acc[mb][2][r] + acc[mb][3][r];

    for (int sb = 0; sb < segsB; ++sb) {
        const int cb = cB0 + sb;
        float colsum[4][4];
        if (sb == segsB - 1) {
#pragma unroll
            for (int mb = 0; mb < 4; ++mb)
#pragma unroll
                for (int r = 0; r < 4; ++r) colsum[mb][r] = rem[mb][r];
        } else {
            const int rb0 = max(soffs[cb]     - j0, n0);
            const int rb1 = min(soffs[cb + 1] - j0, n0 + 64);
#pragma unroll
            for (int mb = 0; mb < 4; ++mb)
#pragma unroll
                for (int r = 0; r < 4; ++r) colsum[mb][r] = 0.f;
#pragma unroll
            for (int nb = 0; nb < 4; ++nb) {
                const int ct = n0 + nb * 16 + lr;
                const bool ic = (ct >= rb0) & (ct < rb1);
#pragma unroll
                for (int mb = 0; mb < 4; ++mb)
#pragma unroll
                    for (int r = 0; r < 4; ++r)
                        colsum[mb][r] += ic ? acc[mb][nb][r] : 0.f;
            }
#pragma unroll
            for (int mb = 0; mb < 4; ++mb)
#pragma unroll
                for (int r = 0; r < 4; ++r) rem[mb][r] -= colsum[mb][r];
        }
        for (int sa = 0; sa < segsA; ++sa) {
            const int ca = cA0 + sa;
            const int ra0 = max(soffs[ca]     - i0, m0);
            const int ra1 = min(soffs[ca + 1] - i0, m0 + 64);
            float v = 0.f;
#pragma unroll
            for (int mb = 0; mb < 4; ++mb) {
                const int rtb = m0 + mb * 16 + lq * 4;
#pragma unroll
                for (int r = 0; r < 4; ++r) {
                    const int rt = rtb + r;
                    const bool ir = (rt >= ra0) & (rt < ra1);
                    v += ir ? colsum[mb][r] : 0.f;
                }
            }
            if (sa < MAXSEG && sb < MAXSEG) {
                red[w][sb * MAXSEG + sa][lane] = v;    // no cross-lane work here
            } else {                                   // overflow fallback (never for this data)
#pragma unroll
                for (int o = 32; o > 0; o >>= 1) v += __shfl_xor(v, o, 64);
                if (lane == 0 && v != 0.f) {
                    const int mn = min(ca, cb), mx = max(ca, cb);
                    atomicAdd(&Ug[mx + ((mn * (2 * C_CLS - 1 - mn)) >> 1)], wscale * v);
                }
            }
        }
    }

    __syncthreads();
    // cooperative reduce: 64 combos x 64 lanes; 4 threads per combo
    {
        const int combo = t >> 2, q = t & 3;
        const int wv = combo >> 4, sl = combo & 15;
        float s = 0.f;
#pragma unroll
        for (int k = 0; k < 16; ++k) s += red[wv][sl][q * 16 + k];
        s += __shfl_xor(s, 1, 64);
        s += __shfl_xor(s, 2, 64);
        const int sa = sl & (MAXSEG - 1), sb = sl >> 2;
        if (q == 0 && sa < meta[wv][2] && sb < meta[wv][3] && s != 0.f) {
            const int ca = meta[wv][0] + sa, cb = meta[wv][1] + sb;
            const int mn = min(ca, cb), mx = max(ca, cb);
            atomicAdd(&Ug[mx + ((mn * (2 * C_CLS - 1 - mn)) >> 1)], wscale * s);
        }
    }
}

// ---- K5: finalize (counts from offs; no label pass) ------------------------
__global__ void finalize_k(const float* __restrict__ U, const int* __restrict__ offs,
                           float* __restrict__ out) {
    __shared__ int   cnt[C_CLS];
    __shared__ float rf[256];
    __shared__ int   ri[256];
    const int t = threadIdx.x;
    if (t < C_CLS) cnt[t] = offs[t + 1] - offs[t];
    __syncthreads();

    float s_intra = 0.f; int n_intra = 0;
    if (t < C_CLS) {
        int c = cnt[t];
        if (c > 1) {
            int idx = t + ((t * (2 * C_CLS - 1 - t)) >> 1);
            s_intra = U[idx] / ((float)c * (float)(c - 1));
            n_intra = 1;
        }
    }
    float s_inter = 0.f; int n_pairs = 0;
    for (int p = t; p < C_CLS * C_CLS; p += 256) {
        int a = p / C_CLS, b2 = p - a * C_CLS;
        if (b2 > a && cnt[a] > 0 && cnt[b2] > 0) {
            int idx = b2 + ((a * (2 * C_CLS - 1 - a)) >> 1);
            s_inter += 0.5f * U[idx] / ((float)cnt[a] * (float)cnt[b2]);
            ++n_pairs;
        }
    }

    rf[t] = s_intra; ri[t] = n_intra; __syncthreads();
    for (int s = 128; s > 0; s >>= 1) {
        if (t < s) { rf[t] += rf[t + s]; ri[t] += ri[t + s]; }
        __syncthreads();
    }
    float intra_sum = rf[0]; int intra_n = ri[0];
    __syncthreads();
    rf[t] = s_inter; ri[t] = n_pairs; __syncthreads();
    for (int s = 128; s > 0; s >>= 1) {
        if (t < s) { rf[t] += rf[t + s]; ri[t] += ri[t + s]; }
        __syncthreads();
    }
    if (t == 0) {
        float inter_sum = rf[0]; int pairs_n = ri[0];
        float intra = (intra_n > 0) ? intra_sum / (float)intra_n : 0.f;
        float inter = (pairs_n > 0) ? inter_sum / (float)pairs_n : 1.f;
        out[0] = fmaxf(intra - inter + 1.0f, 0.f);   // MARGIN = 1.0
    }
}

// ---- launch ----------------------------------------------------------------
extern "C" void kernel_launch(void* const* d_in, const int* in_sizes, int n_in,
                              void* d_out, int out_size, void* d_ws, size_t ws_size,
                              hipStream_t stream) {
    const float* feats  = (const float*)d_in[0];
    const int*   labels = (const int*)d_in[1];
    float* out = (float*)d_out;

    char* p = (char*)d_ws;
    unsigned short* fnb = (unsigned short*)p;  p += (size_t)N_ROWS * D_DIM * sizeof(unsigned short);
    int*   slab      = (int*)p;  p += (size_t)N_ROWS * sizeof(int);
    int*   dest      = (int*)p;  p += (size_t)N_ROWS * sizeof(int);
    int*   hist_part = (int*)p;  p += (size_t)NHB * C_CLS * sizeof(int);
    int*   blockoffs = (int*)p;  p += (size_t)NHB * C_CLS * sizeof(int);
    int*   offs      = (int*)p;  p += 128 * sizeof(int);
    float* Ug        = (float*)p;

    hist_k    <<<NHB, 256, 0, stream>>>(labels, hist_part);
    scan_k    <<<1, 256, 0, stream>>>(hist_part, offs, blockoffs, Ug);
    scatter_k <<<NHB, 256, 0, stream>>>(labels, offs, blockoffs, dest, slab);
    normalize_k<<<N_ROWS / 4, 256, 0, stream>>>(feats, dest, fnb);
    main_k    <<<NBLK, 256, 0, stream>>>(fnb, slab, offs, Ug);
    finalize_k<<<1, 256, 0, stream>>>(Ug, offs, out);
}